// Round 6
// baseline (333.766 us; speedup 1.0000x reference)
//
#include <hip/hip_runtime.h>

#define MBLK 32

typedef __attribute__((ext_vector_type(8))) short bf16x8;
typedef __attribute__((ext_vector_type(4))) float f32x4;

__device__ __forceinline__ unsigned short f2bf(float x){
  unsigned int u = __float_as_uint(x);
  u = u + 0x7FFFu + ((u >> 16) & 1u);
  return (unsigned short)(u >> 16);
}
__device__ __forceinline__ float bf2f(unsigned short s){
  return __uint_as_float(((unsigned int)s) << 16);
}
__device__ __forceinline__ float sigm(float x){
  return __builtin_amdgcn_rcpf(1.0f + __expf(-x));
}
__device__ __forceinline__ float tanh_(float x){
  return 1.0f - 2.0f*__builtin_amdgcn_rcpf(__expf(2.0f*x) + 1.0f);
}

// 1024 threads = 16 waves, 32 samples, 256 blocks (1 block/CU, 4 waves/SIMD).
// Gate-interleaved N-split: wave wv owns units u0=wv*8..+8 for ALL 4 gates as
// two 16-col MFMA tiles: tile0=[i-gate(8)|f-gate(8)], tile1=[g|o]. The 4 gates
// of one unit land in lanes (q,ilo)/(q,ilo+8) of the SAME wave -> shfl_xor(8)
// exchange, nonlin in-register (lo lanes own samples 0-15, hi 16-31), no gl
// LDS roundtrip. Weight B-frags (48 regs) pinned to AGPRs via asm tie so the
// compiler's even VGPR/AGPR split (the R3/R4/R5 spill cause: arch capped at
// 64) holds: AGPR = 48 w + 16 acc, arch ~55. Spill signature: WRITE_SIZE must
// be ~2 MB.
__global__ __launch_bounds__(1024, 4) void traj_kernel(
    const float* __restrict__ img, const float* __restrict__ obs_pos,
    const int* __restrict__ hist, const float* __restrict__ rel,
    const float* __restrict__ h0, const float* __restrict__ W_ih,
    const float* __restrict__ W_hh, const float* __restrict__ b_ih,
    const float* __restrict__ b_hh, const float* __restrict__ eW,
    const float* __restrict__ eb, const float* __restrict__ pW,
    const float* __restrict__ pb, float* __restrict__ out)
{
  __shared__ unsigned short xh[2][MBLK*200];   // [x(64)|h(128)] bf16, stride 200
  __shared__ float relL[MBLK*40];
  __shared__ float pwL[256];                   // pred_W[:, :128]
  __shared__ float eW0[64], eW1[64], ebL[64];
  __shared__ float imgcL[MBLK*2];

  const int tid  = threadIdx.x;
  const int wv   = tid >> 6;
  const int lane = tid & 63;
  const int q    = lane >> 4;
  const int i    = lane & 15;
  const int ilo  = i & 7;
  const bool lo  = (i < 8);
  const int u0   = wv*8;             // this wave's unit base
  const int g0   = blockIdx.x * MBLK;
  const int dm   = tid >> 5;         // sample 0..31 (32 lanes/sample)
  const int i32  = tid & 31;
  const int mbase = lo ? 0 : 16;     // nonlin: lo lanes own samples 0-15

  // ---- cooperative staging ----
  for (int idx = tid; idx < MBLK*40; idx += 1024) relL[idx] = rel[g0*40 + idx];
  if (tid < 256) pwL[tid] = pW[(tid >> 7)*2176 + (tid & 127)];
  if (tid < 64){ eW0[tid] = eW[tid*2]; eW1[tid] = eW[tid*2+1]; ebL[tid] = eb[tid]; }

  // ---- img_embedding @ pred_W[:,128:].T (once; constant over pred steps) ----
  {
    const float* row = img + (size_t)(g0 + dm)*2048 + i32*64;
    const float* p0  = pW + 128 + i32*64;
    const float* p1  = pW + 2176 + 128 + i32*64;
    float s0 = 0.f, s1 = 0.f;
    #pragma unroll
    for (int v = 0; v < 16; v++){
      float4 a  = ((const float4*)row)[v];
      float4 w0 = ((const float4*)p0)[v];
      float4 w1 = ((const float4*)p1)[v];
      s0 += a.x*w0.x + a.y*w0.y + a.z*w0.z + a.w*w0.w;
      s1 += a.x*w1.x + a.y*w1.y + a.z*w1.z + a.w*w1.w;
    }
    #pragma unroll
    for (int msk = 1; msk < 32; msk <<= 1){
      s0 += __shfl_xor(s0, msk);
      s1 += __shfl_xor(s1, msk);
    }
    if (i32 == 0){ imgcL[dm*2] = s0; imgcL[dm*2+1] = s1; }
  }

  // ---- per-lane persistent state: unit u0+ilo, samples mbase+q*4+r ----
  float h0j = h0[u0 + ilo];
  float c_s[4], h_s[4];
  unsigned int thrpk = 0;
  #pragma unroll
  for (int r = 0; r < 4; r++){
    int m = mbase + q*4 + r;
    int hv = hist[g0 + m];
    thrpk |= ((unsigned int)(20 - hv) & 255u) << (r*8);  // keep iff thr > step
    c_s[r] = h0j; h_s[r] = h0j;
    xh[0][m*200 + 64 + u0 + ilo] = f2bf(h0j);
  }

  // ---- biases for this lane's two gate-cols ----
  const int rT0 = lo ? (u0 + ilo)       : (128 + u0 + ilo);  // i | f
  const int rT1 = lo ? (256 + u0 + ilo) : (384 + u0 + ilo);  // g | o
  const float bias0 = b_ih[rT0] + b_hh[rT0];
  const float bias1 = b_ih[rT1] + b_hh[rT1];

  // ---- weight B-fragments, fp32->bf16, pinned into AGPRs ----
  bf16x8 Wa[2][6];
  #pragma unroll
  for (int T = 0; T < 2; T++){
    int row = T ? rT1 : rT0;
    #pragma unroll
    for (int kt = 0; kt < 6; kt++){
      const float* src = (kt < 2) ? (W_ih + row*64  + kt*32     + q*8)
                                  : (W_hh + row*128 + (kt-2)*32 + q*8);
      float4 lov = ((const float4*)src)[0];
      float4 hiv = ((const float4*)src)[1];
      bf16x8 tf;
      tf[0]=(short)f2bf(lov.x); tf[1]=(short)f2bf(lov.y); tf[2]=(short)f2bf(lov.z); tf[3]=(short)f2bf(lov.w);
      tf[4]=(short)f2bf(hiv.x); tf[5]=(short)f2bf(hiv.y); tf[6]=(short)f2bf(hiv.z); tf[7]=(short)f2bf(hiv.w);
      asm("" : "=a"(Wa[T][kt]) : "0"(tf));   // pin to AGPR class
    }
  }

  float pos_r = 0.f;
  if (i32 < 2) pos_r = obs_pos[(size_t)(g0 + dm)*40 + 38 + i32];

  __syncthreads();   // staging + h0 writes visible

  const float ipb0 = imgcL[dm*2]     + pb[0];
  const float ipb1 = imgcL[dm*2 + 1] + pb[1];

  // ---- x_emb(t=1) into xh[0] ----
  {
    int e2 = i32*2;
    float r0 = relL[dm*40 + 2], r1 = relL[dm*40 + 3];
    float a0 = fmaxf(0.f, r0*eW0[e2]   + r1*eW1[e2]   + ebL[e2]);
    float a1 = fmaxf(0.f, r0*eW0[e2+1] + r1*eW1[e2+1] + ebL[e2+1]);
    *((unsigned int*)&xh[0][dm*200 + e2]) =
        (unsigned int)f2bf(a0) | ((unsigned int)f2bf(a1) << 16);
  }

  int b = 0;
  for (int step = 0; step < 49; step++){
    const bool obs = (step < 19);
    __syncthreads();     // xh[b] (x and h) complete

    if (!obs){
      // ---- disp = h @ pwL + imgc + pb; 32 lanes/sample, 4 h-elems each ----
      const unsigned short* hp = &xh[b][dm*200 + 64 + i32*4];
      float s0 = 0.f, s1 = 0.f;
      #pragma unroll
      for (int u = 0; u < 4; u++){
        float hfv = bf2f(hp[u]);
        s0 += hfv * pwL[i32*4 + u];
        s1 += hfv * pwL[128 + i32*4 + u];
      }
      #pragma unroll
      for (int msk = 1; msk < 32; msk <<= 1){
        s0 += __shfl_xor(s0, msk);
        s1 += __shfl_xor(s1, msk);
      }
      float d0 = s0 + ipb0;
      float d1 = s1 + ipb1;
      if (i32 < 2){
        pos_r += (i32 == 0) ? d0 : d1;
        out[(size_t)(g0 + dm)*60 + (size_t)(step - 19)*2 + i32] = pos_r;
      }
      int e2 = i32*2;
      float a0 = fmaxf(0.f, d0*eW0[e2]   + d1*eW1[e2]   + ebL[e2]);
      float a1 = fmaxf(0.f, d0*eW0[e2+1] + d1*eW1[e2+1] + ebL[e2+1]);
      *((unsigned int*)&xh[b][dm*200 + e2]) =
          (unsigned int)f2bf(a0) | ((unsigned int)f2bf(a1) << 16);
      __syncthreads();   // x_emb visible before MFMA reads
    }

    // ---- gates via MFMA: acc[mt][T], samples mt*16+q*4+r, col tile T ----
    f32x4 acc00 = (f32x4){bias0, bias0, bias0, bias0};
    f32x4 acc01 = (f32x4){bias1, bias1, bias1, bias1};
    f32x4 acc10 = acc00;
    f32x4 acc11 = acc01;
    const unsigned short* aP = &xh[b][i*200 + q*8];
    #pragma unroll
    for (int kt = 0; kt < 6; kt++){
      bf16x8 av0 = *((const bf16x8*)(aP + kt*32));          // samples 0..15
      bf16x8 av1 = *((const bf16x8*)(aP + 3200 + kt*32));   // samples 16..31
      acc00 = __builtin_amdgcn_mfma_f32_16x16x32_bf16(av0, Wa[0][kt], acc00, 0, 0, 0);
      acc01 = __builtin_amdgcn_mfma_f32_16x16x32_bf16(av0, Wa[1][kt], acc01, 0, 0, 0);
      acc10 = __builtin_amdgcn_mfma_f32_16x16x32_bf16(av1, Wa[0][kt], acc10, 0, 0, 0);
      acc11 = __builtin_amdgcn_mfma_f32_16x16x32_bf16(av1, Wa[1][kt], acc11, 0, 0, 0);
    }

    // ---- obs: prefetch next step's x_emb (relL only) -> xh[b^1] ----
    if (obs && step < 18){
      int tt = step + 2;
      int e2 = i32*2;
      float r0 = relL[dm*40 + tt*2], r1 = relL[dm*40 + tt*2 + 1];
      float a0 = fmaxf(0.f, r0*eW0[e2]   + r1*eW1[e2]   + ebL[e2]);
      float a1 = fmaxf(0.f, r0*eW0[e2+1] + r1*eW1[e2+1] + ebL[e2+1]);
      *((unsigned int*)&xh[b^1][dm*200 + e2]) =
          (unsigned int)f2bf(a0) | ((unsigned int)f2bf(a1) << 16);
    }

    // ---- in-wave gate exchange: lanes (q,ilo) <-> (q,ilo+8) ----
    f32x4 o00, o01, o10, o11;
    #pragma unroll
    for (int r = 0; r < 4; r++){
      o00[r] = __shfl_xor(acc00[r], 8);
      o01[r] = __shfl_xor(acc01[r], 8);
      o10[r] = __shfl_xor(acc10[r], 8);
      o11[r] = __shfl_xor(acc11[r], 8);
    }

    // ---- nonlinearity: lane owns (unit u0+ilo, samples mbase+q*4+r) ----
    #pragma unroll
    for (int r = 0; r < 4; r++){
      float ig = lo ? acc00[r] : o10[r];
      float fg = lo ? o00[r]   : acc10[r];
      float gg = lo ? acc01[r] : o11[r];
      float og = lo ? o01[r]   : acc11[r];
      float c2 = sigm(fg)*c_s[r] + sigm(ig)*tanh_(gg);
      float h2 = sigm(og)*tanh_(c2);
      if (obs){
        bool keep = (int)((thrpk >> (r*8)) & 255u) > step;
        c2 = keep ? c_s[r] : c2;
        h2 = keep ? h_s[r] : h2;
      }
      c_s[r] = c2; h_s[r] = h2;
      xh[b^1][(mbase + q*4 + r)*200 + 64 + u0 + ilo] = f2bf(h2);
    }

    b ^= 1;
  }
}

extern "C" void kernel_launch(void* const* d_in, const int* in_sizes, int n_in,
                              void* d_out, int out_size, void* d_ws, size_t ws_size,
                              hipStream_t stream){
  const float* img     = (const float*)d_in[0];
  const float* obs_pos = (const float*)d_in[1];
  const int*   hist    = (const int*)d_in[2];
  const float* rel     = (const float*)d_in[3];
  const float* h0      = (const float*)d_in[4];
  const float* W_ih    = (const float*)d_in[5];
  const float* W_hh    = (const float*)d_in[6];
  const float* b_ih    = (const float*)d_in[7];
  const float* b_hh    = (const float*)d_in[8];
  const float* eW      = (const float*)d_in[9];
  const float* eb      = (const float*)d_in[10];
  const float* pW      = (const float*)d_in[11];
  const float* pb      = (const float*)d_in[12];
  float* out = (float*)d_out;
  hipLaunchKernelGGL(traj_kernel, dim3(8192/MBLK), dim3(1024), 0, stream,
                     img, obs_pos, hist, rel, h0, W_ih, W_hh, b_ih, b_hh,
                     eW, eb, pW, pb, out);
}